// Round 8
// baseline (10811.468 us; speedup 1.0000x reference)
//
#include <hip/hip_runtime.h>
#include <hip/hip_fp16.h>
#include <math.h>

#define B_ 256
#define T_ 256
#define RSS_ 12
#define L_ 256
#define FEAT_ 8
#define H_ 128

// ---------------- workspace layout (4-byte slots) ----------------
// PW0: [q=0..30][j=0..511] uint4 : f16 pairs, gate-j row over z0=[12 x-blocks of 10 | h0(128)] (124 pairs)
// PW1: [q=0..15][j] uint4 : f16 pairs, gate-j row over h0(128) (64 pairs)  -> registers
// W1L: [q=0..15][j] uint4 : f16 pairs, gate-j row over h1(128) (64 pairs)  -> LDS
constexpr int OFF_PW0  = 0;                 // 63488 u32
constexpr int OFF_PW1  = OFF_PW0 + 63488;   // 32768
constexpr int OFF_W1L  = OFF_PW1 + 32768;   // 32768
constexpr int OFF_B0   = OFF_W1L + 32768;   // 512 f32
constexpr int OFF_B1   = OFF_B0 + 512;      // 512
constexpr int OFF_QW1T = OFF_B1 + 512;      // [4][64] f32
constexpr int OFF_FC1  = OFF_QW1T + 256;    // [32][64][4] f32 (float4 per (c,j))
constexpr int OFF_K2T4 = OFF_FC1 + 8192;    // [16][256][4] f32
constexpr int OFF_KB   = OFF_K2T4 + 16384;  // [256]
constexpr int OFF_LF   = OFF_KB + 256;      // [256][8] f32
constexpr int OFF_LPX  = OFF_LF + 2048;     // [256]
constexpr int OFF_LPY  = OFF_LPX + 256;
constexpr int OFF_LPZ  = OFF_LPY + 256;
constexpr int OFF_MEAN = OFF_LPZ + 256;     // [8]
constexpr int OFF_PREV0= OFF_MEAN + 8;      // [4]
constexpr int OFF_INT  = OFF_PREV0 + 4;     // ints: ledR[256], cnt[16], idx[12*256]

__device__ __forceinline__ unsigned packh2(float a, float b) {
  const unsigned short lo = __half_as_ushort(__float2half(a));
  const unsigned short hi = __half_as_ushort(__float2half(b));
  return (unsigned)lo | ((unsigned)hi << 16);
}
__device__ __forceinline__ __half2 u2h2(unsigned u){ union { unsigned u; __half2 h; } c; c.u = u; return c.h; }
__device__ __forceinline__ float sigf(float x){ return 1.f/(1.f+expf(-x)); }

// f16-pair dot into f32 acc: unpack + 2 fma (guaranteed-available path)
__device__ __forceinline__ float d2(unsigned w, unsigned z, float acc) {
  const __half2 hw = u2h2(w), hz = u2h2(z);
  acc = fmaf(__low2float(hw),  __low2float(hz),  acc);
  return fmaf(__high2float(hw), __high2float(hz), acc);
}

// ---------------- k_prep ----------------
constexpr int SZ_PW0 = 63488, SZ_PW1 = 32768, SZ_W1L = 32768, SZ_B = 512, SZ_Q = 256, SZ_FC = 8192;
constexpr int TOT_T = SZ_PW0 + SZ_PW1 + SZ_W1L + SZ_B + SZ_B + SZ_Q + SZ_FC;

__global__ void k_prep(const float* __restrict__ Wih0, const float* __restrict__ Whh0,
                       const float* __restrict__ bih0, const float* __restrict__ bhh0,
                       const float* __restrict__ Wih1, const float* __restrict__ Whh1,
                       const float* __restrict__ bih1, const float* __restrict__ bhh1,
                       const float* __restrict__ qW1,  const float* __restrict__ fcW1,
                       float* __restrict__ ws) {
  unsigned* wsu = (unsigned*)ws;
  for (int t = blockIdx.x*blockDim.x + threadIdx.x; t < TOT_T; t += gridDim.x*blockDim.x) {
    int u = t;
    if (u < SZ_PW0) {
      const int k = u & 3, j = (u >> 2) & 511, q = u >> 11;   // q 0..30
      const int p = 4*q + k;                                   // pair 0..123
      float lo, hi;
      if (p < 60) {                 // x-part: block r, entries e0=2*(p%5), e1=e0+1 of [x,a0..a7,0]
        const int r = p / 5, e0 = 2*(p % 5), e1 = e0 + 1;
        lo = Wih0[j*108 + r*9 + e0];                 // e0 in {0,2,4,6,8} always valid
        hi = (e1 <= 8) ? Wih0[j*108 + r*9 + e1] : 0.f;
      } else {                      // h0-part
        const int i0 = 2*(p - 60);
        lo = Whh0[j*128 + i0]; hi = Whh0[j*128 + i0 + 1];
      }
      wsu[OFF_PW0 + u] = packh2(lo, hi); continue;
    } u -= SZ_PW0;
    if (u < SZ_PW1) {
      const int k = u & 3, j = (u >> 2) & 511, q = u >> 11;
      const int i0 = 2*(4*q + k);
      wsu[OFF_PW1 + u] = packh2(Wih1[j*128 + i0], Wih1[j*128 + i0 + 1]); continue;
    } u -= SZ_PW1;
    if (u < SZ_W1L) {
      const int k = u & 3, j = (u >> 2) & 511, q = u >> 11;
      const int i0 = 2*(4*q + k);
      wsu[OFF_W1L + u] = packh2(Whh1[j*128 + i0], Whh1[j*128 + i0 + 1]); continue;
    } u -= SZ_W1L;
    if (u < SZ_B) { ws[OFF_B0+u] = bih0[u]+bhh0[u]; continue; } u -= SZ_B;
    if (u < SZ_B) { ws[OFF_B1+u] = bih1[u]+bhh1[u]; continue; } u -= SZ_B;
    if (u < SZ_Q) { const int c=u>>6, j=u&63; ws[OFF_QW1T+u] = qW1[j*4+c]; continue; } u -= SZ_Q;
    { const int c = u >> 8, rem = u & 255, j = rem >> 2, k = rem & 3;
      ws[OFF_FC1 + u] = fcW1[j*128 + (c<<2) + k]; }
  }
}

// ---------------- k_led (unchanged logic) ----------------
__global__ __launch_bounds__(256) void k_led(const float* __restrict__ gplf,
    const float* __restrict__ encW1, const float* __restrict__ encb1,
    const float* __restrict__ encW2, const float* __restrict__ encb2,
    const float* __restrict__ kW1, const float* __restrict__ kb1,
    const float* __restrict__ kW2, const float* __restrict__ kb2,
    const float* __restrict__ qW2, const float* __restrict__ qb2,
    float* __restrict__ ws) {
  __shared__ float sLF[L_][FEAT_];
  __shared__ float sP[L_][3];
  __shared__ int   sR[L_];
  const int l = threadIdx.x;
  const float p0=gplf[l*4+0], p1=gplf[l*4+1], p2=gplf[l*4+2], fr=gplf[l*4+3];

  float e1[32];
  for (int j=0;j<32;++j) {
    float v = encb1[j] + encW1[j*4+0]*p0 + encW1[j*4+1]*p1 + encW1[j*4+2]*p2 + encW1[j*4+3]*fr;
    e1[j] = fmaxf(v,0.f);
  }
  float lf[8];
  for (int f=0;f<8;++f) {
    float v = encb2[f];
    for (int j=0;j<32;++j) v += encW2[f*32+j]*e1[j];
    lf[f] = fmaxf(v,0.f);
  }
  float kin[11] = {lf[0],lf[1],lf[2],lf[3],lf[4],lf[5],lf[6],lf[7],p0,p1,p2};
  float hh[64];
  for (int j=0;j<64;++j) {
    float v = kb1[j];
    for (int c=0;c<11;++c) v += kW1[j*11+c]*kin[c];
    hh[j]=fmaxf(v,0.f);
  }
  float kk[64];
  for (int d=0;d<64;++d) {
    float v = kb2[d];
    for (int j=0;j<64;++j) v += kW2[d*64+j]*hh[j];
    kk[d]=v;
  }
  float kbv=0.f;
  for (int d=0;d<64;++d) kbv += qb2[d]*kk[d];
  ws[OFF_KB+l]=kbv;
  for (int e=0;e<64;++e) {
    float acc=0.f;
    for (int d=0;d<64;++d) acc += qW2[d*64+e]*kk[d];
    ws[OFF_K2T4 + (e>>2)*1024 + l*4 + (e&3)] = acc;
  }
  for (int f=0;f<8;++f){ ws[OFF_LF+l*8+f]=lf[f]; sLF[l][f]=lf[f]; }
  ws[OFF_LPX+l]=p0; ws[OFF_LPY+l]=p1; ws[OFF_LPZ+l]=p2;
  sP[l][0]=p0; sP[l][1]=p1; sP[l][2]=p2;
  const int r = (int)fr - 1;
  sR[l]=r;
  int* iws = (int*)(ws + OFF_INT);
  iws[l] = r;
  __syncthreads();
  if (l==0) {
    int* cntp = iws + 256;
    int* idxp = cntp + 16;
    int c[12]; for (int r2=0;r2<12;++r2) c[r2]=0;
    for (int i=0;i<L_;++i){ int r2=sR[i]; idxp[r2*256 + c[r2]] = i; c[r2]++; }
    for (int r2=0;r2<12;++r2) cntp[r2]=c[r2];
    float mx=0.f,my=0.f,mz=0.f;
    for (int i=0;i<L_;++i){mx+=sP[i][0];my+=sP[i][1];mz+=sP[i][2];}
    ws[OFF_PREV0+0]=mx/(float)L_; ws[OFF_PREV0+1]=my/(float)L_; ws[OFF_PREV0+2]=mz/(float)L_;
    for (int f=0;f<8;++f){ float s=0.f; for (int i=0;i<L_;++i) s+=sLF[i][f]; ws[OFF_MEAN+f]=s/(float)L_; }
  }
}

// ---------------- main kernel: 512 threads, weights register+LDS resident ----------------
__global__ __launch_bounds__(512,2) void k_main(const float* __restrict__ rss,
    const float* __restrict__ qb1, const float* __restrict__ lng, const float* __restrict__ lnb,
    const float* __restrict__ fcb1, const float* __restrict__ fcW2, const float* __restrict__ fcb2,
    const float* __restrict__ ws, float* __restrict__ out) {
  const int b = blockIdx.x, tid = threadIdx.x;
  const int lane = tid & 63, wave = tid >> 6;
  const int j = tid;   // gate index 0..511

  __shared__ uint4 sW1L[8192];                 // 128 KB: LSTM1 h1-half weights, [q][j]
  __shared__ unsigned sLFh[1024];              // led_feat f16 pairs [l][4]
  __shared__ float sLPx[256], sLPy[256], sLPz[256];
  __shared__ float sKB[256];
  __shared__ float sQ[256], sqb1v[64];
  __shared__ float sLNG[128], sLNB[128];
  __shared__ float sfcb1[64], sfcW2v[192], sfcb2v[4];
  __shared__ float sMEANv[8];
  __shared__ __align__(16) unsigned sz0h[124]; // z0 f16 pairs: [12 x-blocks ×5 | h0 ×64]
  __shared__ __align__(16) unsigned sz1h[128]; // z1 f16 pairs: [h0 ×64 | h1 ×64]
  __shared__ float sc0[128], sc1[128];
  __shared__ __align__(16) float sa[12][68];
  __shared__ float ssv[256];
  __shared__ float sg[512];
  __shared__ __align__(16) float syv[128];
  __shared__ float sprev[4];
  __shared__ int   sledR[256], scnt[16];
  __shared__ unsigned short sidx16[12*256];

  // ---- register-resident weights (named, loaded once) ----
  const uint4* PW0 = (const uint4*)((const unsigned*)ws + OFF_PW0);
  const uint4* PW1 = (const uint4*)((const unsigned*)ws + OFF_PW1);
#define LW0(Q) const uint4 w0_##Q = PW0[Q*512 + j];
#define LW1(Q) const uint4 w1_##Q = PW1[Q*512 + j];
  LW0(0) LW0(1) LW0(2) LW0(3) LW0(4) LW0(5) LW0(6) LW0(7) LW0(8) LW0(9)
  LW0(10) LW0(11) LW0(12) LW0(13) LW0(14) LW0(15) LW0(16) LW0(17) LW0(18) LW0(19)
  LW0(20) LW0(21) LW0(22) LW0(23) LW0(24) LW0(25) LW0(26) LW0(27) LW0(28) LW0(29) LW0(30)
  LW1(0) LW1(1) LW1(2) LW1(3) LW1(4) LW1(5) LW1(6) LW1(7)
  LW1(8) LW1(9) LW1(10) LW1(11) LW1(12) LW1(13) LW1(14) LW1(15)
  const float biasA = ws[OFF_B0 + j];
  const float biasB = ws[OFF_B1 + j];

  // ---- one-time LDS staging ----
  {
    const uint4* W1Lg = (const uint4*)((const unsigned*)ws + OFF_W1L);
    for (int u = tid; u < 8192; u += 512) sW1L[u] = W1Lg[u];
    for (int u = tid; u < 1024; u += 512) sLFh[u] = packh2(ws[OFF_LF+2*u], ws[OFF_LF+2*u+1]);
  }
  if (tid < 256) { sLPx[tid]=ws[OFF_LPX+tid]; sLPy[tid]=ws[OFF_LPY+tid]; sLPz[tid]=ws[OFF_LPZ+tid];
                   sKB[tid]=ws[OFF_KB+tid]; sQ[tid]=ws[OFF_QW1T+tid]; }
  if (tid < 64) { sqb1v[tid]=qb1[tid]; sfcb1[tid]=fcb1[tid]; }
  if (tid < 128){ sLNG[tid]=lng[tid]; sLNB[tid]=lnb[tid]; sc0[tid]=0.f; sc1[tid]=0.f; sz1h[tid]=0u; }
  if (tid < 192) sfcW2v[tid]=fcW2[tid];
  if (tid < 3)  { sfcb2v[tid]=fcb2[tid]; sprev[tid]=ws[OFF_PREV0+tid]; }
  if (tid < 8)   sMEANv[tid]=ws[OFF_MEAN+tid];
  if (tid < 64)  sz0h[60+tid]=0u;
  {
    const int* iws = (const int*)(ws + OFF_INT);
    if (tid < 256) sledR[tid]=iws[tid];
    if (tid < 12)  scnt[tid]=iws[256+tid];
    for (int u = tid; u < 12*256; u += 512) sidx16[u] = (unsigned short)iws[272+u];
  }
  __syncthreads();

  const float* rb = rss + (size_t)b*T_*12;
  // rss prefetch registers: wave w owns row w (and w+8 if w<4)
  float x0 = rb[wave];
  float x1 = (wave < 4) ? rb[wave+8] : 0.f;

  const float4* K2g = (const float4*)(ws + OFF_K2T4);
  const float4* F1g = (const float4*)(ws + OFF_FC1);
  const uint4*  z0u4 = (const uint4*)sz0h;
  const uint4*  z1u4 = (const uint4*)sz1h;

  for (int t = 0; t < T_; ++t) {
    // prefetch next step's rss (consumed next iteration)
    float xn0 = 0.f, xn1 = 0.f;
    if (t+1 < T_) {
      xn0 = rb[(t+1)*12 + wave];
      if (wave < 4) xn1 = rb[(t+1)*12 + wave+8];
    }
    const float px = sprev[0], py = sprev[1], pz = sprev[2];

    // (a) relu(q_in @ q_W1^T + q_b1): wave w does row w (and w+8)
    {
      float v = sqb1v[lane] + x0*sQ[lane] + px*sQ[64+lane] + py*sQ[128+lane] + pz*sQ[192+lane];
      sa[wave][lane] = fmaxf(v, 0.f);
      if (wave < 4) {
        float v2 = sqb1v[lane] + x1*sQ[lane] + px*sQ[64+lane] + py*sQ[128+lane] + pz*sQ[192+lane];
        sa[wave+8][lane] = fmaxf(v2, 0.f);
      }
    }
    __syncthreads();

    // (b) scores per LED: folded-key dot (K2 streamed from L2) + distance-log
    if (tid < 256) {
      const int l = tid, r = sledR[l];
      float a0 = sKB[l], a1 = 0.f;
      const float4* ar4 = (const float4*)&sa[r][0];
      #pragma unroll 1
      for (int cc = 0; cc < 4; ++cc) {
        const float4 wA = K2g[(cc*4+0)*256 + l];
        const float4 wB = K2g[(cc*4+1)*256 + l];
        const float4 wC = K2g[(cc*4+2)*256 + l];
        const float4 wD = K2g[(cc*4+3)*256 + l];
        const float4 aA = ar4[cc*4+0], aB = ar4[cc*4+1], aC = ar4[cc*4+2], aD = ar4[cc*4+3];
        a0=fmaf(aA.x,wA.x,a0); a1=fmaf(aA.y,wA.y,a1); a0=fmaf(aA.z,wA.z,a0); a1=fmaf(aA.w,wA.w,a1);
        a0=fmaf(aB.x,wB.x,a0); a1=fmaf(aB.y,wB.y,a1); a0=fmaf(aB.z,wB.z,a0); a1=fmaf(aB.w,wB.w,a1);
        a0=fmaf(aC.x,wC.x,a0); a1=fmaf(aC.y,wC.y,a1); a0=fmaf(aC.z,wC.z,a0); a1=fmaf(aC.w,wC.w,a1);
        a0=fmaf(aD.x,wD.x,a0); a1=fmaf(aD.y,wD.y,a1); a0=fmaf(aD.z,wD.z,a0); a1=fmaf(aD.w,wD.w,a1);
      }
      const float dx = px-sLPx[tid], dy = py-sLPy[tid], dz = pz-sLPz[tid];
      ssv[tid] = a0 + a1 - 0.5f*logf(dx*dx+dy*dy+dz*dz + 1e-8f);
    }
    __syncthreads();

    // (c) masked softmax + aggregation; pack x-block f16 pairs into sz0h
    for (int rr = 0; rr < 2; ++rr) {
      if (rr == 1 && wave >= 4) break;
      const int r = wave + rr*8;
      const int cnt = scnt[r];
      float vmax = -3.402823466e38f;
      for (int c = lane; c < cnt; c += 64) vmax = fmaxf(vmax, ssv[sidx16[r*256+c]]);
      #pragma unroll
      for (int o = 32; o > 0; o >>= 1) vmax = fmaxf(vmax, __shfl_xor(vmax, o));
      float ps=0.f, p0=0.f,p1=0.f,p2=0.f,p3=0.f,p4=0.f,p5=0.f,p6=0.f,p7=0.f;
      for (int c = lane; c < cnt; c += 64) {
        const int li = sidx16[r*256+c];
        const float p = expf(ssv[li]-vmax);
        ps += p;
        const unsigned* lf = sLFh + li*4;
        const __half2 A=u2h2(lf[0]), Bq=u2h2(lf[1]), C=u2h2(lf[2]), D=u2h2(lf[3]);
        p0 += p*__low2float(A); p1 += p*__high2float(A);
        p2 += p*__low2float(Bq); p3 += p*__high2float(Bq);
        p4 += p*__low2float(C); p5 += p*__high2float(C);
        p6 += p*__low2float(D); p7 += p*__high2float(D);
      }
      #pragma unroll
      for (int o = 32; o > 0; o >>= 1) {
        ps += __shfl_xor(ps,o);
        p0 += __shfl_xor(p0,o); p1 += __shfl_xor(p1,o);
        p2 += __shfl_xor(p2,o); p3 += __shfl_xor(p3,o);
        p4 += __shfl_xor(p4,o); p5 += __shfl_xor(p5,o);
        p6 += __shfl_xor(p6,o); p7 += __shfl_xor(p7,o);
      }
      if (lane == 0) {
        const float xv = rr ? x1 : x0;
        float a0v,a1v,a2v,a3v,a4v,a5v,a6v,a7v;
        if (cnt > 0) {
          const float inv = 1.f/ps;
          a0v=p0*inv; a1v=p1*inv; a2v=p2*inv; a3v=p3*inv;
          a4v=p4*inv; a5v=p5*inv; a6v=p6*inv; a7v=p7*inv;
        } else {
          a0v=sMEANv[0]; a1v=sMEANv[1]; a2v=sMEANv[2]; a3v=sMEANv[3];
          a4v=sMEANv[4]; a5v=sMEANv[5]; a6v=sMEANv[6]; a7v=sMEANv[7];
        }
        sz0h[r*5+0] = packh2(xv,  a0v);
        sz0h[r*5+1] = packh2(a1v, a2v);
        sz0h[r*5+2] = packh2(a3v, a4v);
        sz0h[r*5+3] = packh2(a5v, a6v);
        sz0h[r*5+4] = packh2(a7v, 0.f);
      }
    }
    __syncthreads();

    // (d1) LSTM0 gates: register f16 weights × LDS f16 z (uniform reads), 4 accumulators
    {
      float g0 = biasA, g1 = 0.f, g2 = 0.f, g3 = 0.f;
#define D0(Q) { const uint4 Z = z0u4[Q]; \
      g0 = d2(w0_##Q.x, Z.x, g0); g1 = d2(w0_##Q.y, Z.y, g1); \
      g2 = d2(w0_##Q.z, Z.z, g2); g3 = d2(w0_##Q.w, Z.w, g3); }
      D0(0) D0(1) D0(2) D0(3) D0(4) D0(5) D0(6) D0(7) D0(8) D0(9)
      D0(10) D0(11) D0(12) D0(13) D0(14) D0(15) D0(16) D0(17) D0(18) D0(19)
      D0(20) D0(21) D0(22) D0(23) D0(24) D0(25) D0(26) D0(27) D0(28) D0(29) D0(30)
      sg[j] = (g0+g1)+(g2+g3);
    }
    __syncthreads();

    // (d2) LSTM0 nonlinearity: wave 0, 2 h-values/thread, pack h2 pairs
    if (tid < 64) {
      const int v = tid;
      const float iA=sigf(sg[2*v]),     iB=sigf(sg[2*v+1]);
      const float fA=sigf(sg[128+2*v]), fB=sigf(sg[128+2*v+1]);
      const float gA=tanhf(sg[256+2*v]),gB=tanhf(sg[256+2*v+1]);
      const float oA=sigf(sg[384+2*v]), oB=sigf(sg[384+2*v+1]);
      const float cA = fA*sc0[2*v]   + iA*gA;
      const float cB = fB*sc0[2*v+1] + iB*gB;
      sc0[2*v] = cA; sc0[2*v+1] = cB;
      const float hA = oA*tanhf(cA), hB = oB*tanhf(cB);
      const unsigned hp = packh2(hA, hB);
      sz0h[60+v] = hp; sz1h[v] = hp;
    }
    __syncthreads();

    // (e1) LSTM1 gates: h0-half from registers, h1-half from LDS weights
    {
      float g0 = biasB, g1 = 0.f, g2 = 0.f, g3 = 0.f;
#define E1(Q) { const uint4 Z = z1u4[Q]; \
      g0 = d2(w1_##Q.x, Z.x, g0); g1 = d2(w1_##Q.y, Z.y, g1); \
      g2 = d2(w1_##Q.z, Z.z, g2); g3 = d2(w1_##Q.w, Z.w, g3); }
      E1(0) E1(1) E1(2) E1(3) E1(4) E1(5) E1(6) E1(7)
      E1(8) E1(9) E1(10) E1(11) E1(12) E1(13) E1(14) E1(15)
      #pragma unroll 4
      for (int q = 0; q < 16; ++q) {
        const uint4 W = sW1L[q*512 + j];
        const uint4 Z = z1u4[16+q];
        g0 = d2(W.x, Z.x, g0); g1 = d2(W.y, Z.y, g1);
        g2 = d2(W.z, Z.z, g2); g3 = d2(W.w, Z.w, g3);
      }
      sg[j] = (g0+g1)+(g2+g3);
    }
    __syncthreads();

    // (e2+f+g) wave 0: LSTM1 nonlinearity + LayerNorm + FC head (no internal barriers)
    if (tid < 64) {
      const int v = tid;
      const float iA=sigf(sg[2*v]),     iB=sigf(sg[2*v+1]);
      const float fA=sigf(sg[128+2*v]), fB=sigf(sg[128+2*v+1]);
      const float gA=tanhf(sg[256+2*v]),gB=tanhf(sg[256+2*v+1]);
      const float oA=sigf(sg[384+2*v]), oB=sigf(sg[384+2*v+1]);
      const float cA = fA*sc1[2*v]   + iA*gA;
      const float cB = fB*sc1[2*v+1] + iB*gB;
      sc1[2*v] = cA; sc1[2*v+1] = cB;
      const float hA = oA*tanhf(cA), hB = oB*tanhf(cB);
      sz1h[64+v] = packh2(hA, hB);
      // LayerNorm stats across the wave
      float s = hA + hB, qs = hA*hA + hB*hB;
      #pragma unroll
      for (int o = 32; o > 0; o >>= 1) { s += __shfl_xor(s,o); qs += __shfl_xor(qs,o); }
      const float mu = s*(1.f/128.f);
      const float rs = 1.f/sqrtf(qs*(1.f/128.f) - mu*mu + 1e-5f);
      const float yA = (hA-mu)*rs*sLNG[2*v] + sLNB[2*v];
      const float yB = (hB-mu)*rs*sLNG[2*v+1] + sLNB[2*v+1];
      syv[2*v] = yA; syv[2*v+1] = yB;
      // FC1 (weights streamed from L2) — same wave, compiler inserts lgkm waits for syv
      float acc = sfcb1[v], acc2 = 0.f;
      const float4* sy4 = (const float4*)syv;
      #pragma unroll 1
      for (int cc = 0; cc < 8; ++cc) {
        const float4 wA = F1g[(cc*4+0)*64 + v];
        const float4 wB = F1g[(cc*4+1)*64 + v];
        const float4 wC = F1g[(cc*4+2)*64 + v];
        const float4 wD = F1g[(cc*4+3)*64 + v];
        const float4 zA = sy4[cc*4+0], zB = sy4[cc*4+1], zC = sy4[cc*4+2], zD = sy4[cc*4+3];
        acc=fmaf(wA.x,zA.x,acc); acc2=fmaf(wA.y,zA.y,acc2); acc=fmaf(wA.z,zA.z,acc); acc2=fmaf(wA.w,zA.w,acc2);
        acc=fmaf(wB.x,zB.x,acc); acc2=fmaf(wB.y,zB.y,acc2); acc=fmaf(wB.z,zB.z,acc); acc2=fmaf(wB.w,zB.w,acc2);
        acc=fmaf(wC.x,zC.x,acc); acc2=fmaf(wC.y,zC.y,acc2); acc=fmaf(wC.z,zC.z,acc); acc2=fmaf(wC.w,zC.w,acc2);
        acc=fmaf(wD.x,zD.x,acc); acc2=fmaf(wD.y,zD.y,acc2); acc=fmaf(wD.z,zD.z,acc); acc2=fmaf(wD.w,zD.w,acc2);
      }
      const float f1 = fmaxf(acc+acc2, 0.f);
      float a0 = sfcW2v[v]*f1, a1 = sfcW2v[64+v]*f1, a2 = sfcW2v[128+v]*f1;
      #pragma unroll
      for (int o = 32; o > 0; o >>= 1) {
        a0 += __shfl_xor(a0,o); a1 += __shfl_xor(a1,o); a2 += __shfl_xor(a2,o);
      }
      if (v < 3) {
        const float r = (v==0 ? a0 : (v==1 ? a1 : a2)) + sfcb2v[v];
        out[((size_t)b*T_+t)*3+v] = r;
        sprev[v] = r;
      }
    }
    __syncthreads();

    x0 = xn0; x1 = xn1;
  }
}

extern "C" void kernel_launch(void* const* d_in, const int* in_sizes, int n_in,
                              void* d_out, int out_size, void* d_ws, size_t ws_size,
                              hipStream_t stream) {
  const float* rss   = (const float*)d_in[0];
  const float* gplf  = (const float*)d_in[1];
  const float* encW1 = (const float*)d_in[2];
  const float* encb1 = (const float*)d_in[3];
  const float* encW2 = (const float*)d_in[4];
  const float* encb2 = (const float*)d_in[5];
  const float* qW1   = (const float*)d_in[6];
  const float* qb1   = (const float*)d_in[7];
  const float* qW2   = (const float*)d_in[8];
  const float* qb2   = (const float*)d_in[9];
  const float* kW1   = (const float*)d_in[10];
  const float* kb1   = (const float*)d_in[11];
  const float* kW2   = (const float*)d_in[12];
  const float* kb2   = (const float*)d_in[13];
  const float* Wih0  = (const float*)d_in[14];
  const float* Whh0  = (const float*)d_in[15];
  const float* bih0  = (const float*)d_in[16];
  const float* bhh0  = (const float*)d_in[17];
  const float* Wih1  = (const float*)d_in[18];
  const float* Whh1  = (const float*)d_in[19];
  const float* bih1  = (const float*)d_in[20];
  const float* bhh1  = (const float*)d_in[21];
  const float* lng   = (const float*)d_in[22];
  const float* lnb   = (const float*)d_in[23];
  const float* fcW1  = (const float*)d_in[24];
  const float* fcb1  = (const float*)d_in[25];
  const float* fcW2  = (const float*)d_in[26];
  const float* fcb2  = (const float*)d_in[27];
  float* ws   = (float*)d_ws;
  float* outp = (float*)d_out;

  hipLaunchKernelGGL(k_prep, dim3(256), dim3(256), 0, stream,
                     Wih0,Whh0,bih0,bhh0,Wih1,Whh1,bih1,bhh1,qW1,fcW1,ws);
  hipLaunchKernelGGL(k_led, dim3(1), dim3(256), 0, stream,
                     gplf,encW1,encb1,encW2,encb2,kW1,kb1,kW2,kb2,qW2,qb2,ws);
  hipLaunchKernelGGL(k_main, dim3(B_), dim3(512), 0, stream,
                     rss,qb1,lng,lnb,fcb1,fcW2,fcb2,ws,outp);
}

// Round 9
// 2588.576 us; speedup vs baseline: 4.1766x; 4.1766x over previous
//
#include <hip/hip_runtime.h>
#include <hip/hip_fp16.h>
#include <math.h>

#define B_ 256
#define T_ 256
#define RSS_ 12
#define L_ 256
#define FEAT_ 8
#define H_ 128

// ---------------- workspace layout (4-byte slots) ----------------
constexpr int OFF_PW0  = 0;                 // 63488 u32 : [q=0..30][j] uint4 f16-pairs, z0 gate rows
constexpr int OFF_PW1  = OFF_PW0 + 63488;   // 32768    : [q=0..15][j] uint4, Wih1 (h0) gate rows -> regs
constexpr int OFF_W1L  = OFF_PW1 + 32768;   // 32768    : [q=0..15][j] uint4, Whh1 (h1) gate rows -> LDS
constexpr int OFF_B0   = OFF_W1L + 32768;   // 512 f32
constexpr int OFF_B1   = OFF_B0 + 512;      // 512
constexpr int OFF_QW1T = OFF_B1 + 512;      // [4][64] f32
constexpr int OFF_FC1  = OFF_QW1T + 256;    // [32][64][4] f32
constexpr int OFF_K2T4 = OFF_FC1 + 8192;    // [16][256][4] f32
constexpr int OFF_KB   = OFF_K2T4 + 16384;  // [256]
constexpr int OFF_LF   = OFF_KB + 256;      // [256][8] f32
constexpr int OFF_LPX  = OFF_LF + 2048;     // [256]
constexpr int OFF_LPY  = OFF_LPX + 256;
constexpr int OFF_LPZ  = OFF_LPY + 256;
constexpr int OFF_MEAN = OFF_LPZ + 256;     // [8]
constexpr int OFF_PREV0= OFF_MEAN + 8;      // [4]
constexpr int OFF_INT  = OFF_PREV0 + 4;     // ints: ledR[256], cnt[16], idx[12*256]

__device__ __forceinline__ unsigned packh2(float a, float b) {
  const unsigned short lo = __half_as_ushort(__float2half(a));
  const unsigned short hi = __half_as_ushort(__float2half(b));
  return (unsigned)lo | ((unsigned)hi << 16);
}
__device__ __forceinline__ __half2 u2h2(unsigned u){ union { unsigned u; __half2 h; } c; c.u = u; return c.h; }
__device__ __forceinline__ float sigf(float x){ return 1.f/(1.f+expf(-x)); }

// f16-pair dot with f32 accumulate: v_dot2_f32_f16 when available (1 instr), else cvt+fma
#if __has_builtin(__builtin_amdgcn_fdot2)
typedef _Float16 h2v __attribute__((ext_vector_type(2)));
__device__ __forceinline__ float d2(unsigned w, unsigned z, float acc) {
  union { unsigned u; h2v h; } cw, cz; cw.u = w; cz.u = z;
  return __builtin_amdgcn_fdot2(cw.h, cz.h, acc, false);
}
#else
__device__ __forceinline__ float d2(unsigned w, unsigned z, float acc) {
  const __half2 hw = u2h2(w), hz = u2h2(z);
  acc = fmaf(__low2float(hw),  __low2float(hz),  acc);
  return fmaf(__high2float(hw), __high2float(hz), acc);
}
#endif

// ---------------- k_prep ----------------
constexpr int SZ_PW0 = 63488, SZ_PW1 = 32768, SZ_W1L = 32768, SZ_B = 512, SZ_Q = 256, SZ_FC = 8192;
constexpr int TOT_T = SZ_PW0 + SZ_PW1 + SZ_W1L + SZ_B + SZ_B + SZ_Q + SZ_FC;

__global__ void k_prep(const float* __restrict__ Wih0, const float* __restrict__ Whh0,
                       const float* __restrict__ bih0, const float* __restrict__ bhh0,
                       const float* __restrict__ Wih1, const float* __restrict__ Whh1,
                       const float* __restrict__ bih1, const float* __restrict__ bhh1,
                       const float* __restrict__ qW1,  const float* __restrict__ fcW1,
                       float* __restrict__ ws) {
  unsigned* wsu = (unsigned*)ws;
  for (int t = blockIdx.x*blockDim.x + threadIdx.x; t < TOT_T; t += gridDim.x*blockDim.x) {
    int u = t;
    if (u < SZ_PW0) {
      const int k = u & 3, j = (u >> 2) & 511, q = u >> 11;   // q 0..30
      const int p = 4*q + k;                                   // pair 0..123
      float lo, hi;
      if (p < 60) {                 // x-part: block r, z=[x,a0..a7,0]
        const int r = p / 5, e0 = 2*(p % 5), e1 = e0 + 1;
        lo = Wih0[j*108 + r*9 + e0];
        hi = (e1 <= 8) ? Wih0[j*108 + r*9 + e1] : 0.f;
      } else {                      // h0-part
        const int i0 = 2*(p - 60);
        lo = Whh0[j*128 + i0]; hi = Whh0[j*128 + i0 + 1];
      }
      wsu[OFF_PW0 + u] = packh2(lo, hi); continue;
    } u -= SZ_PW0;
    if (u < SZ_PW1) {
      const int k = u & 3, j = (u >> 2) & 511, q = u >> 11;
      const int i0 = 2*(4*q + k);
      wsu[OFF_PW1 + u] = packh2(Wih1[j*128 + i0], Wih1[j*128 + i0 + 1]); continue;
    } u -= SZ_PW1;
    if (u < SZ_W1L) {
      const int k = u & 3, j = (u >> 2) & 511, q = u >> 11;
      const int i0 = 2*(4*q + k);
      wsu[OFF_W1L + u] = packh2(Whh1[j*128 + i0], Whh1[j*128 + i0 + 1]); continue;
    } u -= SZ_W1L;
    if (u < SZ_B) { ws[OFF_B0+u] = bih0[u]+bhh0[u]; continue; } u -= SZ_B;
    if (u < SZ_B) { ws[OFF_B1+u] = bih1[u]+bhh1[u]; continue; } u -= SZ_B;
    if (u < SZ_Q) { const int c=u>>6, j=u&63; ws[OFF_QW1T+u] = qW1[j*4+c]; continue; } u -= SZ_Q;
    { const int c = u >> 8, rem = u & 255, j = rem >> 2, k = rem & 3;
      ws[OFF_FC1 + u] = fcW1[j*128 + (c<<2) + k]; }
  }
}

// ---------------- k_led (unchanged logic) ----------------
__global__ __launch_bounds__(256) void k_led(const float* __restrict__ gplf,
    const float* __restrict__ encW1, const float* __restrict__ encb1,
    const float* __restrict__ encW2, const float* __restrict__ encb2,
    const float* __restrict__ kW1, const float* __restrict__ kb1,
    const float* __restrict__ kW2, const float* __restrict__ kb2,
    const float* __restrict__ qW2, const float* __restrict__ qb2,
    float* __restrict__ ws) {
  __shared__ float sLF[L_][FEAT_];
  __shared__ float sP[L_][3];
  __shared__ int   sR[L_];
  const int l = threadIdx.x;
  const float p0=gplf[l*4+0], p1=gplf[l*4+1], p2=gplf[l*4+2], fr=gplf[l*4+3];

  float e1[32];
  for (int j=0;j<32;++j) {
    float v = encb1[j] + encW1[j*4+0]*p0 + encW1[j*4+1]*p1 + encW1[j*4+2]*p2 + encW1[j*4+3]*fr;
    e1[j] = fmaxf(v,0.f);
  }
  float lf[8];
  for (int f=0;f<8;++f) {
    float v = encb2[f];
    for (int j=0;j<32;++j) v += encW2[f*32+j]*e1[j];
    lf[f] = fmaxf(v,0.f);
  }
  float kin[11] = {lf[0],lf[1],lf[2],lf[3],lf[4],lf[5],lf[6],lf[7],p0,p1,p2};
  float hh[64];
  for (int j=0;j<64;++j) {
    float v = kb1[j];
    for (int c=0;c<11;++c) v += kW1[j*11+c]*kin[c];
    hh[j]=fmaxf(v,0.f);
  }
  float kk[64];
  for (int d=0;d<64;++d) {
    float v = kb2[d];
    for (int j=0;j<64;++j) v += kW2[d*64+j]*hh[j];
    kk[d]=v;
  }
  float kbv=0.f;
  for (int d=0;d<64;++d) kbv += qb2[d]*kk[d];
  ws[OFF_KB+l]=kbv;
  for (int e=0;e<64;++e) {
    float acc=0.f;
    for (int d=0;d<64;++d) acc += qW2[d*64+e]*kk[d];
    ws[OFF_K2T4 + (e>>2)*1024 + l*4 + (e&3)] = acc;
  }
  for (int f=0;f<8;++f){ ws[OFF_LF+l*8+f]=lf[f]; sLF[l][f]=lf[f]; }
  ws[OFF_LPX+l]=p0; ws[OFF_LPY+l]=p1; ws[OFF_LPZ+l]=p2;
  sP[l][0]=p0; sP[l][1]=p1; sP[l][2]=p2;
  const int r = (int)fr - 1;
  sR[l]=r;
  int* iws = (int*)(ws + OFF_INT);
  iws[l] = r;
  __syncthreads();
  if (l==0) {
    int* cntp = iws + 256;
    int* idxp = cntp + 16;
    int c[12]; for (int r2=0;r2<12;++r2) c[r2]=0;
    for (int i=0;i<L_;++i){ int r2=sR[i]; idxp[r2*256 + c[r2]] = i; c[r2]++; }
    for (int r2=0;r2<12;++r2) cntp[r2]=c[r2];
    float mx=0.f,my=0.f,mz=0.f;
    for (int i=0;i<L_;++i){mx+=sP[i][0];my+=sP[i][1];mz+=sP[i][2];}
    ws[OFF_PREV0+0]=mx/(float)L_; ws[OFF_PREV0+1]=my/(float)L_; ws[OFF_PREV0+2]=mz/(float)L_;
    for (int f=0;f<8;++f){ float s=0.f; for (int i=0;i<L_;++i) s+=sLF[i][f]; ws[OFF_MEAN+f]=s/(float)L_; }
  }
}

// ---------------- main kernel: 512 threads, (512,1) -> up to 512 VGPR, no spill ----------------
__global__ __launch_bounds__(512,1) void k_main(const float* __restrict__ rss,
    const float* __restrict__ qb1, const float* __restrict__ lng, const float* __restrict__ lnb,
    const float* __restrict__ fcb1, const float* __restrict__ fcW2, const float* __restrict__ fcb2,
    const float* __restrict__ ws, float* __restrict__ out) {
  const int b = blockIdx.x, tid = threadIdx.x;
  const int lane = tid & 63, wave = tid >> 6;
  const int j = tid;   // gate index 0..511

  __shared__ uint4 sW1L[8192];                 // 128 KB: LSTM1 h1-half weights, [q][j]
  __shared__ unsigned sLFh[1024];              // led_feat f16 pairs [l][4]
  __shared__ float sLPx[256], sLPy[256], sLPz[256];
  __shared__ float sKB[256];
  __shared__ float sQ[256], sqb1v[64];
  __shared__ float sLNG[128], sLNB[128];
  __shared__ float sfcb1[64], sfcW2v[192], sfcb2v[4];
  __shared__ float sMEANv[8];
  __shared__ __align__(16) unsigned sz0h[124]; // z0 f16 pairs: [12 x-blocks ×5 | h0 ×64]
  __shared__ __align__(16) unsigned sz1h[128]; // z1 f16 pairs: [h0 ×64 | h1 ×64]
  __shared__ float sc0[128], sc1[128];
  __shared__ __align__(16) float sa[12][68];
  __shared__ float ssv[256];
  __shared__ float sg[512];
  __shared__ __align__(16) float syv[128];
  __shared__ float sprev[4];
  __shared__ int   sledR[256], scnt[16];
  __shared__ unsigned short sidx16[12*256];

  // ---- register-resident weights (named, loaded once) ----
  const uint4* PW0 = (const uint4*)((const unsigned*)ws + OFF_PW0);
  const uint4* PW1 = (const uint4*)((const unsigned*)ws + OFF_PW1);
#define LW0(Q) const uint4 w0_##Q = PW0[Q*512 + j];
#define LW1(Q) const uint4 w1_##Q = PW1[Q*512 + j];
  LW0(0) LW0(1) LW0(2) LW0(3) LW0(4) LW0(5) LW0(6) LW0(7) LW0(8) LW0(9)
  LW0(10) LW0(11) LW0(12) LW0(13) LW0(14) LW0(15) LW0(16) LW0(17) LW0(18) LW0(19)
  LW0(20) LW0(21) LW0(22) LW0(23) LW0(24) LW0(25) LW0(26) LW0(27) LW0(28) LW0(29) LW0(30)
  LW1(0) LW1(1) LW1(2) LW1(3) LW1(4) LW1(5) LW1(6) LW1(7)
  LW1(8) LW1(9) LW1(10) LW1(11) LW1(12) LW1(13) LW1(14) LW1(15)
  const float biasA = ws[OFF_B0 + j];
  const float biasB = ws[OFF_B1 + j];

  // ---- one-time LDS staging ----
  {
    const uint4* W1Lg = (const uint4*)((const unsigned*)ws + OFF_W1L);
    for (int u = tid; u < 8192; u += 512) sW1L[u] = W1Lg[u];
    for (int u = tid; u < 1024; u += 512) sLFh[u] = packh2(ws[OFF_LF+2*u], ws[OFF_LF+2*u+1]);
  }
  if (tid < 256) { sLPx[tid]=ws[OFF_LPX+tid]; sLPy[tid]=ws[OFF_LPY+tid]; sLPz[tid]=ws[OFF_LPZ+tid];
                   sKB[tid]=ws[OFF_KB+tid]; sQ[tid]=ws[OFF_QW1T+tid]; }
  if (tid < 64) { sqb1v[tid]=qb1[tid]; sfcb1[tid]=fcb1[tid]; }
  if (tid < 128){ sLNG[tid]=lng[tid]; sLNB[tid]=lnb[tid]; sc0[tid]=0.f; sc1[tid]=0.f; sz1h[tid]=0u; }
  if (tid < 192) sfcW2v[tid]=fcW2[tid];
  if (tid < 3)  { sfcb2v[tid]=fcb2[tid]; sprev[tid]=ws[OFF_PREV0+tid]; }
  if (tid < 8)   sMEANv[tid]=ws[OFF_MEAN+tid];
  if (tid < 64)  sz0h[60+tid]=0u;
  {
    const int* iws = (const int*)(ws + OFF_INT);
    if (tid < 256) sledR[tid]=iws[tid];
    if (tid < 12)  scnt[tid]=iws[256+tid];
    for (int u = tid; u < 12*256; u += 512) sidx16[u] = (unsigned short)iws[272+u];
  }
  __syncthreads();

  const float* rb = rss + (size_t)b*T_*12;
  float x0 = rb[wave];
  float x1 = (wave < 4) ? rb[wave+8] : 0.f;

  const float4* K2g = (const float4*)(ws + OFF_K2T4);
  const float4* F1g = (const float4*)(ws + OFF_FC1);
  const uint4*  z0u4 = (const uint4*)sz0h;
  const uint4*  z1u4 = (const uint4*)sz1h;

  for (int t = 0; t < T_; ++t) {
    float xn0 = 0.f, xn1 = 0.f;
    if (t+1 < T_) {
      xn0 = rb[(t+1)*12 + wave];
      if (wave < 4) xn1 = rb[(t+1)*12 + wave+8];
    }
    const float px = sprev[0], py = sprev[1], pz = sprev[2];

    // (a) relu(q_in @ q_W1^T + q_b1)
    {
      float v = sqb1v[lane] + x0*sQ[lane] + px*sQ[64+lane] + py*sQ[128+lane] + pz*sQ[192+lane];
      sa[wave][lane] = fmaxf(v, 0.f);
      if (wave < 4) {
        float v2 = sqb1v[lane] + x1*sQ[lane] + px*sQ[64+lane] + py*sQ[128+lane] + pz*sQ[192+lane];
        sa[wave+8][lane] = fmaxf(v2, 0.f);
      }
    }
    __syncthreads();

    // (b) scores per LED
    if (tid < 256) {
      const int l = tid, r = sledR[l];
      float a0 = sKB[l], a1 = 0.f;
      const float4* ar4 = (const float4*)&sa[r][0];
      #pragma unroll 1
      for (int cc = 0; cc < 4; ++cc) {
        const float4 wA = K2g[(cc*4+0)*256 + l];
        const float4 wB = K2g[(cc*4+1)*256 + l];
        const float4 wC = K2g[(cc*4+2)*256 + l];
        const float4 wD = K2g[(cc*4+3)*256 + l];
        const float4 aA = ar4[cc*4+0], aB = ar4[cc*4+1], aC = ar4[cc*4+2], aD = ar4[cc*4+3];
        a0=fmaf(aA.x,wA.x,a0); a1=fmaf(aA.y,wA.y,a1); a0=fmaf(aA.z,wA.z,a0); a1=fmaf(aA.w,wA.w,a1);
        a0=fmaf(aB.x,wB.x,a0); a1=fmaf(aB.y,wB.y,a1); a0=fmaf(aB.z,wB.z,a0); a1=fmaf(aB.w,wB.w,a1);
        a0=fmaf(aC.x,wC.x,a0); a1=fmaf(aC.y,wC.y,a1); a0=fmaf(aC.z,wC.z,a0); a1=fmaf(aC.w,wC.w,a1);
        a0=fmaf(aD.x,wD.x,a0); a1=fmaf(aD.y,wD.y,a1); a0=fmaf(aD.z,wD.z,a0); a1=fmaf(aD.w,wD.w,a1);
      }
      const float dx = px-sLPx[tid], dy = py-sLPy[tid], dz = pz-sLPz[tid];
      ssv[tid] = a0 + a1 - 0.5f*logf(dx*dx+dy*dy+dz*dz + 1e-8f);
    }
    __syncthreads();

    // (c) masked softmax + aggregation; pack z0 x-blocks as f16 pairs
    for (int rr = 0; rr < 2; ++rr) {
      if (rr == 1 && wave >= 4) break;
      const int r = wave + rr*8;
      const int cnt = scnt[r];
      float vmax = -3.402823466e38f;
      for (int c = lane; c < cnt; c += 64) vmax = fmaxf(vmax, ssv[sidx16[r*256+c]]);
      #pragma unroll
      for (int o = 32; o > 0; o >>= 1) vmax = fmaxf(vmax, __shfl_xor(vmax, o));
      float ps=0.f, p0=0.f,p1=0.f,p2=0.f,p3=0.f,p4=0.f,p5=0.f,p6=0.f,p7=0.f;
      for (int c = lane; c < cnt; c += 64) {
        const int li = sidx16[r*256+c];
        const float p = expf(ssv[li]-vmax);
        ps += p;
        const unsigned* lf = sLFh + li*4;
        const __half2 A=u2h2(lf[0]), Bq=u2h2(lf[1]), C=u2h2(lf[2]), D=u2h2(lf[3]);
        p0 += p*__low2float(A); p1 += p*__high2float(A);
        p2 += p*__low2float(Bq); p3 += p*__high2float(Bq);
        p4 += p*__low2float(C); p5 += p*__high2float(C);
        p6 += p*__low2float(D); p7 += p*__high2float(D);
      }
      #pragma unroll
      for (int o = 32; o > 0; o >>= 1) {
        ps += __shfl_xor(ps,o);
        p0 += __shfl_xor(p0,o); p1 += __shfl_xor(p1,o);
        p2 += __shfl_xor(p2,o); p3 += __shfl_xor(p3,o);
        p4 += __shfl_xor(p4,o); p5 += __shfl_xor(p5,o);
        p6 += __shfl_xor(p6,o); p7 += __shfl_xor(p7,o);
      }
      if (lane == 0) {
        const float xv = rr ? x1 : x0;
        float a0v,a1v,a2v,a3v,a4v,a5v,a6v,a7v;
        if (cnt > 0) {
          const float inv = 1.f/ps;
          a0v=p0*inv; a1v=p1*inv; a2v=p2*inv; a3v=p3*inv;
          a4v=p4*inv; a5v=p5*inv; a6v=p6*inv; a7v=p7*inv;
        } else {
          a0v=sMEANv[0]; a1v=sMEANv[1]; a2v=sMEANv[2]; a3v=sMEANv[3];
          a4v=sMEANv[4]; a5v=sMEANv[5]; a6v=sMEANv[6]; a7v=sMEANv[7];
        }
        sz0h[r*5+0] = packh2(xv,  a0v);
        sz0h[r*5+1] = packh2(a1v, a2v);
        sz0h[r*5+2] = packh2(a3v, a4v);
        sz0h[r*5+3] = packh2(a5v, a6v);
        sz0h[r*5+4] = packh2(a7v, 0.f);
      }
    }
    __syncthreads();

    // (d1) LSTM0 gates: register f16 weights × uniform LDS z, fdot2, 4 accumulators
    {
      float g0 = biasA, g1 = 0.f, g2 = 0.f, g3 = 0.f;
#define D0(Q) { const uint4 Z = z0u4[Q]; \
      g0 = d2(w0_##Q.x, Z.x, g0); g1 = d2(w0_##Q.y, Z.y, g1); \
      g2 = d2(w0_##Q.z, Z.z, g2); g3 = d2(w0_##Q.w, Z.w, g3); }
      D0(0) D0(1) D0(2) D0(3) D0(4) D0(5) D0(6) D0(7) D0(8) D0(9)
      D0(10) D0(11) D0(12) D0(13) D0(14) D0(15) D0(16) D0(17) D0(18) D0(19)
      D0(20) D0(21) D0(22) D0(23) D0(24) D0(25) D0(26) D0(27) D0(28) D0(29) D0(30)
      sg[j] = (g0+g1)+(g2+g3);
    }
    __syncthreads();

    // (d2) LSTM0 nonlinearity
    if (tid < 64) {
      const int v = tid;
      const float iA=sigf(sg[2*v]),     iB=sigf(sg[2*v+1]);
      const float fA=sigf(sg[128+2*v]), fB=sigf(sg[128+2*v+1]);
      const float gA=tanhf(sg[256+2*v]),gB=tanhf(sg[256+2*v+1]);
      const float oA=sigf(sg[384+2*v]), oB=sigf(sg[384+2*v+1]);
      const float cA = fA*sc0[2*v]   + iA*gA;
      const float cB = fB*sc0[2*v+1] + iB*gB;
      sc0[2*v] = cA; sc0[2*v+1] = cB;
      const float hA = oA*tanhf(cA), hB = oB*tanhf(cB);
      const unsigned hp = packh2(hA, hB);
      sz0h[60+v] = hp; sz1h[v] = hp;
    }
    __syncthreads();

    // (e1) LSTM1 gates: h0-half register weights, h1-half LDS weights
    {
      float g0 = biasB, g1 = 0.f, g2 = 0.f, g3 = 0.f;
#define E1(Q) { const uint4 Z = z1u4[Q]; \
      g0 = d2(w1_##Q.x, Z.x, g0); g1 = d2(w1_##Q.y, Z.y, g1); \
      g2 = d2(w1_##Q.z, Z.z, g2); g3 = d2(w1_##Q.w, Z.w, g3); }
      E1(0) E1(1) E1(2) E1(3) E1(4) E1(5) E1(6) E1(7)
      E1(8) E1(9) E1(10) E1(11) E1(12) E1(13) E1(14) E1(15)
      #pragma unroll 4
      for (int q = 0; q < 16; ++q) {
        const uint4 W = sW1L[q*512 + j];
        const uint4 Z = z1u4[16+q];
        g0 = d2(W.x, Z.x, g0); g1 = d2(W.y, Z.y, g1);
        g2 = d2(W.z, Z.z, g2); g3 = d2(W.w, Z.w, g3);
      }
      sg[j] = (g0+g1)+(g2+g3);
    }
    __syncthreads();

    // (e2+f+g) wave 0: LSTM1 nonlinearity + LayerNorm + FC head
    if (tid < 64) {
      const int v = tid;
      const float iA=sigf(sg[2*v]),     iB=sigf(sg[2*v+1]);
      const float fA=sigf(sg[128+2*v]), fB=sigf(sg[128+2*v+1]);
      const float gA=tanhf(sg[256+2*v]),gB=tanhf(sg[256+2*v+1]);
      const float oA=sigf(sg[384+2*v]), oB=sigf(sg[384+2*v+1]);
      const float cA = fA*sc1[2*v]   + iA*gA;
      const float cB = fB*sc1[2*v+1] + iB*gB;
      sc1[2*v] = cA; sc1[2*v+1] = cB;
      const float hA = oA*tanhf(cA), hB = oB*tanhf(cB);
      sz1h[64+v] = packh2(hA, hB);
      float s = hA + hB, qs = hA*hA + hB*hB;
      #pragma unroll
      for (int o = 32; o > 0; o >>= 1) { s += __shfl_xor(s,o); qs += __shfl_xor(qs,o); }
      const float mu = s*(1.f/128.f);
      const float rs = 1.f/sqrtf(qs*(1.f/128.f) - mu*mu + 1e-5f);
      const float yA = (hA-mu)*rs*sLNG[2*v] + sLNB[2*v];
      const float yB = (hB-mu)*rs*sLNG[2*v+1] + sLNB[2*v+1];
      syv[2*v] = yA; syv[2*v+1] = yB;
      float acc = sfcb1[v], acc2 = 0.f;
      const float4* sy4 = (const float4*)syv;
      #pragma unroll 1
      for (int cc = 0; cc < 8; ++cc) {
        const float4 wA = F1g[(cc*4+0)*64 + v];
        const float4 wB = F1g[(cc*4+1)*64 + v];
        const float4 wC = F1g[(cc*4+2)*64 + v];
        const float4 wD = F1g[(cc*4+3)*64 + v];
        const float4 zA = sy4[cc*4+0], zB = sy4[cc*4+1], zC = sy4[cc*4+2], zD = sy4[cc*4+3];
        acc=fmaf(wA.x,zA.x,acc); acc2=fmaf(wA.y,zA.y,acc2); acc=fmaf(wA.z,zA.z,acc); acc2=fmaf(wA.w,zA.w,acc2);
        acc=fmaf(wB.x,zB.x,acc); acc2=fmaf(wB.y,zB.y,acc2); acc=fmaf(wB.z,zB.z,acc); acc2=fmaf(wB.w,zB.w,acc2);
        acc=fmaf(wC.x,zC.x,acc); acc2=fmaf(wC.y,zC.y,acc2); acc=fmaf(wC.z,zC.z,acc); acc2=fmaf(wC.w,zC.w,acc2);
        acc=fmaf(wD.x,zD.x,acc); acc2=fmaf(wD.y,zD.y,acc2); acc=fmaf(wD.z,zD.z,acc); acc2=fmaf(wD.w,zD.w,acc2);
      }
      const float f1 = fmaxf(acc+acc2, 0.f);
      float a0 = sfcW2v[v]*f1, a1 = sfcW2v[64+v]*f1, a2 = sfcW2v[128+v]*f1;
      #pragma unroll
      for (int o = 32; o > 0; o >>= 1) {
        a0 += __shfl_xor(a0,o); a1 += __shfl_xor(a1,o); a2 += __shfl_xor(a2,o);
      }
      if (v < 3) {
        const float r = (v==0 ? a0 : (v==1 ? a1 : a2)) + sfcb2v[v];
        out[((size_t)b*T_+t)*3+v] = r;
        sprev[v] = r;
      }
    }
    __syncthreads();

    x0 = xn0; x1 = xn1;
  }
}

extern "C" void kernel_launch(void* const* d_in, const int* in_sizes, int n_in,
                              void* d_out, int out_size, void* d_ws, size_t ws_size,
                              hipStream_t stream) {
  const float* rss   = (const float*)d_in[0];
  const float* gplf  = (const float*)d_in[1];
  const float* encW1 = (const float*)d_in[2];
  const float* encb1 = (const float*)d_in[3];
  const float* encW2 = (const float*)d_in[4];
  const float* encb2 = (const float*)d_in[5];
  const float* qW1   = (const float*)d_in[6];
  const float* qb1   = (const float*)d_in[7];
  const float* qW2   = (const float*)d_in[8];
  const float* qb2   = (const float*)d_in[9];
  const float* kW1   = (const float*)d_in[10];
  const float* kb1   = (const float*)d_in[11];
  const float* kW2   = (const float*)d_in[12];
  const float* kb2   = (const float*)d_in[13];
  const float* Wih0  = (const float*)d_in[14];
  const float* Whh0  = (const float*)d_in[15];
  const float* bih0  = (const float*)d_in[16];
  const float* bhh0  = (const float*)d_in[17];
  const float* Wih1  = (const float*)d_in[18];
  const float* Whh1  = (const float*)d_in[19];
  const float* bih1  = (const float*)d_in[20];
  const float* bhh1  = (const float*)d_in[21];
  const float* lng   = (const float*)d_in[22];
  const float* lnb   = (const float*)d_in[23];
  const float* fcW1  = (const float*)d_in[24];
  const float* fcb1  = (const float*)d_in[25];
  const float* fcW2  = (const float*)d_in[26];
  const float* fcb2  = (const float*)d_in[27];
  float* ws   = (float*)d_ws;
  float* outp = (float*)d_out;

  hipLaunchKernelGGL(k_prep, dim3(256), dim3(256), 0, stream,
                     Wih0,Whh0,bih0,bhh0,Wih1,Whh1,bih1,bhh1,qW1,fcW1,ws);
  hipLaunchKernelGGL(k_led, dim3(1), dim3(256), 0, stream,
                     gplf,encW1,encb1,encW2,encb2,kW1,kb1,kW2,kb2,qW2,qb2,ws);
  hipLaunchKernelGGL(k_main, dim3(B_), dim3(512), 0, stream,
                     rss,qb1,lng,lnb,fcb1,fcW2,fcb2,ws,outp);
}